// Round 11
// baseline (191.757 us; speedup 1.0000x reference)
//
#include <hip/hip_runtime.h>

#define TT 512
#define BB 512
#define NN 64
#define LN2F 0.69314718055994530942f

typedef _Float16 half8_t __attribute__((ext_vector_type(8)));
typedef float    f32x4   __attribute__((ext_vector_type(4)));

union AFrag { int u[4]; half8_t h; };

__device__ __forceinline__ float wave_max(float v) {
    #pragma unroll
    for (int off = 32; off > 0; off >>= 1)
        v = fmaxf(v, __shfl_xor(v, off, 64));
    return v;
}

__device__ __forceinline__ float wave_sum(float v) {
    #pragma unroll
    for (int off = 32; off > 0; off >>= 1)
        v += __shfl_xor(v, off, 64);
    return v;
}

__device__ __forceinline__ int wave_sum_i(int v) {
    #pragma unroll
    for (int off = 32; off > 0; off >>= 1)
        v += __shfl_xor(v, off, 64);
    return v;
}

__device__ __forceinline__ float bcast_lane(float v, int lane) {
    return __uint_as_float(__builtin_amdgcn_readlane(__float_as_uint(v), lane));
}

// async global->LDS DMA, 4 bytes/lane: LDS dest = uniform base + lane*4.
__device__ __forceinline__ void async4(const float* g, float* l) {
    __builtin_amdgcn_global_load_lds(
        (const __attribute__((address_space(1))) unsigned int*)g,
        (__attribute__((address_space(3))) unsigned int*)l,
        4, 0, 0);
}

// Zero the scalar output (harness poisons d_out with 0xAA before every launch).
__global__ void zero_kernel(float* __restrict__ out) {
    if (threadIdx.x == 0 && blockIdx.x == 0) out[0] = 0.0f;
}

// Forward algorithm in the EXP domain, matvec via MFMA, emit staged through a
// 2-half LDS ring (global_load_lds DMA). Serial chain per step (the wall is
// 511 x chain; occupancy can't help):
//   cvt_pkrtz -> 8 ds_bpermute -> 8 MFMA (C-chained K-halves) -> select ->
//   pair-swap -> scale.
// r11 trims vs r10 (~470 cyc/step):
//  - state kept as PAIR (u_{2m}, u_{2m+1}) f32 per lane: pack is ONE cvt_pkrtz
//    (chain head loses DPP+2 cndmask);
//  - rescale exponent e taken from the PRE-w select value (+4 guard;
//    sel-spread<=2^7.7, w<=2^8 => packed u <= 2^12.7 < f16 max), so
//    readfirstlane->SALU->ldexp(w) runs PARALLEL to the y-pair swap and the
//    tail is a single v_mul per element. e_sum += e+2 stays exact for any e.
__global__ __launch_bounds__(64) void crf_fwd_kernel(
    const float* __restrict__ emit,
    const float* __restrict__ trans,
    const float* __restrict__ strans,
    const float* __restrict__ etrans,
    const int*   __restrict__ target,
    const void*  __restrict__ maskp,
    float* __restrict__ out)
{
    const int b = blockIdx.x;
    const int k = threadIdx.x;

    __shared__ float sem[2][8][NN];   // 4 KB emit ring: [half][slot][state]

    const int*           mi32 = (const int*)maskp;
    const unsigned char* mi8  = (const unsigned char*)maskp;
    // mask[0,:] is all-true (lengths >= 1): byte encoding -> word0 == 0x01010101.
    const bool bytemode = (mi32[0] == 0x01010101);

    // len[b] = sum_t mask[t,b] (mask monotone per column) — one-time cost.
    int cnt = 0;
    #pragma unroll
    for (int i = 0; i < TT / 64; ++i) {
        const size_t tb = (size_t)(i * 64 + k) * BB + b;
        cnt += bytemode ? (mi8[tb] != 0) : (mi32[tb] != 0);
    }
    const int len = wave_sum_i(cnt);   // wave-uniform

    const int q   = k >> 4;
    const int nlo = k & 15;
    const int kp  = k & ~1;            // pair base index 2m
    const bool odd  = (k & 1)  != 0;
    const bool bit4 = (k & 16) != 0;
    const bool bit5 = (k & 32) != 0;

    const float* ecol = emit + (size_t)b * NN + k;   // row stride BB*NN

    // Prologue: DMA rows 1..8 into half 0 (rows 1..8 always exist: TT=512).
    #pragma unroll
    for (int s = 0; s < 8; ++s)
        async4(ecol + (size_t)(1 + s) * BB * NN, &sem[0][s][0]);

    // B fragments: Bf[g][kh], element j = 0.25*exp(trans[(32kh+8q+j)][16g+nlo]).
    // A-layout: A[m=lane&15][k2=8*(lane>>4)+j]; all 16 A-rows replicated.
    // C/D: col=lane&15, all rows equal -> lane k selects group k>>4 via cndmasks.
    half8_t Bf[4][2];
    #pragma unroll
    for (int g = 0; g < 4; ++g) {
        #pragma unroll
        for (int kh = 0; kh < 2; ++kh) {
            AFrag bf;
            #pragma unroll
            for (int jp = 0; jp < 4; ++jp) {
                const int krow = 32 * kh + 8 * q + 2 * jp;
                const float e0 = 0.25f * __expf(trans[(krow + 0) * NN + 16 * g + nlo]);
                const float e1 = 0.25f * __expf(trans[(krow + 1) * NN + 16 * g + nlo]);
                bf.u[jp] = __builtin_bit_cast(int, __builtin_amdgcn_cvt_pkrtz(e0, e1));
            }
            Bf[g][kh] = bf.h;
        }
    }

    // bpermute byte-addresses: A frag (kh, reg r) needs the f16 pair
    // (u_{32kh+8q+2r}, u_{...+2r+1}), held by (even) source lane 32kh+8q+2r.
    int addrs[8];
    #pragma unroll
    for (int kh = 0; kh < 2; ++kh)
        #pragma unroll
        for (int r = 0; r < 4; ++r)
            addrs[4 * kh + r] = 128 * kh + 32 * q + 8 * r;

    const f32x4 zero4 = {0.f, 0.f, 0.f, 0.f};

    // t = 0: pair state ue = u_{2m}, uo = u_{2m+1}; u = exp(alpha0 - m0).
    const float2 a0p = *(const float2*)(emit + (size_t)b * NN + kp);
    const float2 stp = *(const float2*)(strans + kp);
    const float ae = a0p.x + stp.x;
    const float ao = a0p.y + stp.y;
    const float m0 = bcast_lane(ae, 0);   // lane0's even element = state 0
    float ue = __expf(ae - m0);
    float uo = __expf(ao - m0);
    int e_sum = 0;

    // One step: y = (u . 0.25E); e = exp2(y_0)+4; u' = (y*w)*2^{-e}; e_sum += e+2.
    auto do_step = [&](float we, float wo) {
        // chain head: ONE pack op (lanes 2m,2m+1 produce identical pairs;
        // bpermute sources are the even lanes)
        const int pkv = __builtin_bit_cast(int, __builtin_amdgcn_cvt_pkrtz(ue, uo));

        // gather A fragments (8 bpermutes, in-order LDS pipe)
        AFrag a0f, a1f;
        #pragma unroll
        for (int r = 0; r < 4; ++r) {
            a0f.u[r] = __builtin_amdgcn_ds_bpermute(addrs[r],     pkv);
            a1f.u[r] = __builtin_amdgcn_ds_bpermute(addrs[4 + r], pkv);
        }

        // y = u * 0.25E : 4 column groups; K-halves chained through C.
        const f32x4 accA0 = __builtin_amdgcn_mfma_f32_16x16x32_f16(a0f.h, Bf[0][0], zero4, 0, 0, 0);
        const f32x4 accA1 = __builtin_amdgcn_mfma_f32_16x16x32_f16(a0f.h, Bf[1][0], zero4, 0, 0, 0);
        const f32x4 accA2 = __builtin_amdgcn_mfma_f32_16x16x32_f16(a0f.h, Bf[2][0], zero4, 0, 0, 0);
        const f32x4 accA3 = __builtin_amdgcn_mfma_f32_16x16x32_f16(a0f.h, Bf[3][0], zero4, 0, 0, 0);
        const f32x4 acc0 = __builtin_amdgcn_mfma_f32_16x16x32_f16(a1f.h, Bf[0][1], accA0, 0, 0, 0);
        const f32x4 acc1 = __builtin_amdgcn_mfma_f32_16x16x32_f16(a1f.h, Bf[1][1], accA1, 0, 0, 0);
        const f32x4 acc2 = __builtin_amdgcn_mfma_f32_16x16x32_f16(a1f.h, Bf[2][1], accA2, 0, 0, 0);
        const f32x4 acc3 = __builtin_amdgcn_mfma_f32_16x16x32_f16(a1f.h, Bf[3][1], accA3, 0, 0, 0);

        // lane k holds y_{k} after group select (all D rows identical)
        const float sLo  = bit4 ? acc1[0] : acc0[0];
        const float sHi  = bit4 ? acc3[0] : acc2[0];
        const float yown = bit5 ? sHi : sLo;

        // e from lane0's PRE-w y (+4 guard) — runs parallel to the pair swap
        const int e = (int)((__builtin_amdgcn_readfirstlane(__float_as_uint(yown)) >> 23) & 0xff) - 127 + 4;
        const float se = ldexpf(we, -e);
        const float so = ldexpf(wo, -e);

        // form the y-pair: neighbor via DPP quad_perm(1,0,3,2) = xor-1 swap
        const float ynb = __int_as_float(
            __builtin_amdgcn_mov_dpp(__float_as_int(yown), 0xB1, 0xF, 0xF, true));
        const float ye = odd ? ynb : yown;
        const float yo = odd ? yown : ynb;

        ue = ye * se;
        uo = yo * so;
        e_sum += e + 2;   // +2 restores the 0.25=2^-2 folded into B (exact)
    };

    int t = 1;
    int half = 0;
    // Invariant at block top: rows t..t+7 are in sem[half][0..7] — their DMAs
    // were issued >= 1 block (~8 steps) ago, so the vmcnt wait is free.
    for (; t + 8 <= len; t += 8) {
        // (1) read this block's emit PAIRS (ds_read_b64, broadcast per pair)
        const float2 vp0 = *(const float2*)&sem[half][0][kp];
        const float2 vp1 = *(const float2*)&sem[half][1][kp];
        const float2 vp2 = *(const float2*)&sem[half][2][kp];
        const float2 vp3 = *(const float2*)&sem[half][3][kp];
        const float2 vp4 = *(const float2*)&sem[half][4][kp];
        const float2 vp5 = *(const float2*)&sem[half][5][kp];
        const float2 vp6 = *(const float2*)&sem[half][6][kp];
        const float2 vp7 = *(const float2*)&sem[half][7][kp];

        // (2) issue next block's DMAs into the other half (clamped at TT-1)
        #pragma unroll
        for (int s = 0; s < 8; ++s) {
            const int tf = (t + 8 + s < TT) ? (t + 8 + s) : (TT - 1);
            async4(ecol + (size_t)tf * BB * NN, &sem[half ^ 1][s][0]);
        }

        // (3) w-pairs off the u-chain, then 8 MFMA steps
        const float we0 = __expf(vp0.x), wo0 = __expf(vp0.y);
        const float we1 = __expf(vp1.x), wo1 = __expf(vp1.y);
        const float we2 = __expf(vp2.x), wo2 = __expf(vp2.y);
        const float we3 = __expf(vp3.x), wo3 = __expf(vp3.y);
        const float we4 = __expf(vp4.x), wo4 = __expf(vp4.y);
        const float we5 = __expf(vp5.x), wo5 = __expf(vp5.y);
        const float we6 = __expf(vp6.x), wo6 = __expf(vp6.y);
        const float we7 = __expf(vp7.x), wo7 = __expf(vp7.y);
        do_step(we0, wo0); do_step(we1, wo1); do_step(we2, wo2); do_step(we3, wo3);
        do_step(we4, wo4); do_step(we5, wo5); do_step(we6, wo6); do_step(we7, wo7);

        half ^= 1;
    }

    // Remainder (< 8 steps): rows t..len-1 are already in sem[half][...].
    for (int s = 0; t < len; ++t, ++s) {
        const float2 vp = *(const float2*)&sem[half][s][kp];
        do_step(__expf(vp.x), __expf(vp.y));
    }

    // logZ_b = S + logsumexp_k(log u_k + etrans_k). Lanes 2m,2m+1 hold the
    // SAME pair -> zero odd lanes' contribution to avoid double counting.
    const float2 etp = *(const float2*)(etrans + kp);
    const float lae = __logf(ue) + etp.x;   // u==0 -> -inf -> exp -> 0: fine
    const float lao = __logf(uo) + etp.y;
    const float m2 = wave_max(fmaxf(lae, lao));
    float contrib = __expf(lae - m2) + __expf(lao - m2);
    if (odd) contrib = 0.f;
    const float sm = wave_sum(contrib);
    const float logZ_b = m0 + LN2F * (float)e_sum + m2 + __logf(sm);

    // ---- fused gold score for batch b: lane k covers t = 64*i + k ----
    int tvals[TT / 64];
    #pragma unroll
    for (int i = 0; i < TT / 64; ++i)
        tvals[i] = target[(size_t)(64 * i + k) * BB + b];

    float g = 0.f;
    int prev_last = 0;
    #pragma unroll
    for (int i = 0; i < TT / 64; ++i) {
        const int tt = 64 * i + k;
        const int tgt = tvals[i];
        int tprev = __shfl_up(tvals[i], 1, 64);
        if (k == 0) tprev = prev_last;                       // carry across i
        prev_last = __builtin_amdgcn_readlane(tvals[i], 63);
        if (tt < len) {
            float v = emit[((size_t)tt * BB + b) * NN + tgt];
            v += (tt == 0) ? strans[tgt] : trans[tprev * NN + tgt];
            if (tt == len - 1) v += etrans[tgt];
            g += v;
        }
    }
    g = wave_sum(g);

    if (k == 0) atomicAdd(out, logZ_b - g);
}

extern "C" void kernel_launch(void* const* d_in, const int* in_sizes, int n_in,
                              void* d_out, int out_size, void* d_ws, size_t ws_size,
                              hipStream_t stream) {
    const float* emit   = (const float*)d_in[0];
    const float* trans  = (const float*)d_in[1];
    const float* strans = (const float*)d_in[2];
    const float* etrans = (const float*)d_in[3];
    const int*   target = (const int*)d_in[4];
    const void*  mask   = d_in[5];
    float* out = (float*)d_out;

    hipLaunchKernelGGL(zero_kernel, dim3(1), dim3(64), 0, stream, out);
    hipLaunchKernelGGL(crf_fwd_kernel, dim3(BB), dim3(64), 0, stream,
                       emit, trans, strans, etrans, target, mask, out);
}

// Round 12
// 182.851 us; speedup vs baseline: 1.0487x; 1.0487x over previous
//
#include <hip/hip_runtime.h>

#define TT 512
#define BB 512
#define NN 64
#define LN2F 0.69314718055994530942f

typedef _Float16 half8_t __attribute__((ext_vector_type(8)));
typedef float    f32x4   __attribute__((ext_vector_type(4)));

union AFrag { int u[4]; half8_t h; };

__device__ __forceinline__ float wave_max(float v) {
    #pragma unroll
    for (int off = 32; off > 0; off >>= 1)
        v = fmaxf(v, __shfl_xor(v, off, 64));
    return v;
}

__device__ __forceinline__ float wave_sum(float v) {
    #pragma unroll
    for (int off = 32; off > 0; off >>= 1)
        v += __shfl_xor(v, off, 64);
    return v;
}

__device__ __forceinline__ int wave_sum_i(int v) {
    #pragma unroll
    for (int off = 32; off > 0; off >>= 1)
        v += __shfl_xor(v, off, 64);
    return v;
}

__device__ __forceinline__ float bcast_lane(float v, int lane) {
    return __uint_as_float(__builtin_amdgcn_readlane(__float_as_uint(v), lane));
}

// async global->LDS DMA, 4 bytes/lane: LDS dest = uniform base + lane*4.
__device__ __forceinline__ void async4(const float* g, float* l) {
    __builtin_amdgcn_global_load_lds(
        (const __attribute__((address_space(1))) unsigned int*)g,
        (__attribute__((address_space(3))) unsigned int*)l,
        4, 0, 0);
}

// Zero the scalar output (harness poisons d_out with 0xAA before every launch).
__global__ void zero_kernel(float* __restrict__ out) {
    if (threadIdx.x == 0 && blockIdx.x == 0) out[0] = 0.0f;
}

// Forward algorithm in the EXP domain, matvec via MFMA, emit staged through a
// 2-half LDS ring (global_load_lds DMA). Per-step cost model (r4/r11 verified):
//   ~4.7 cyc x issue-slots  +  bpermute latency ~130  +  MFMA pipe 8x19.4.
// r12 = r10 (best, ~470 cyc/step) + two slot/chain trims:
//  - pack is cvt_pkrtz(u, dpp_xor1(u)) with NO pe/po cndmasks: bpermute
//    sources are even lanes only (addr lane = 8q+2r), odd lanes' pkv unused;
//  - rescale exponent e taken from the PRE-w select value (+4 guard:
//    sel*2^-e in [2^-4,2^-3), w<=2^8, spread<=2^7.7 => u <= 2^12.7 < f16 max)
//    so readfirstlane->s_sub overlaps the v_mul by wloc. e_sum += e+2 exact.
__global__ __launch_bounds__(64) void crf_fwd_kernel(
    const float* __restrict__ emit,
    const float* __restrict__ trans,
    const float* __restrict__ strans,
    const float* __restrict__ etrans,
    const int*   __restrict__ target,
    const void*  __restrict__ maskp,
    float* __restrict__ out)
{
    const int b = blockIdx.x;
    const int k = threadIdx.x;

    __shared__ float sem[2][8][NN];   // 4 KB emit ring: [half][slot][state]

    const int*           mi32 = (const int*)maskp;
    const unsigned char* mi8  = (const unsigned char*)maskp;
    // mask[0,:] is all-true (lengths >= 1): byte encoding -> word0 == 0x01010101.
    const bool bytemode = (mi32[0] == 0x01010101);

    // len[b] = sum_t mask[t,b] (mask monotone per column) — one-time cost.
    int cnt = 0;
    #pragma unroll
    for (int i = 0; i < TT / 64; ++i) {
        const size_t tb = (size_t)(i * 64 + k) * BB + b;
        cnt += bytemode ? (mi8[tb] != 0) : (mi32[tb] != 0);
    }
    const int len = wave_sum_i(cnt);   // wave-uniform

    const int q   = k >> 4;
    const int nlo = k & 15;
    const bool bit4 = (k & 16) != 0;
    const bool bit5 = (k & 32) != 0;

    const float* ecol = emit + (size_t)b * NN + k;   // row stride BB*NN

    // Prologue: DMA rows 1..8 into half 0 (rows 1..8 always exist: TT=512).
    #pragma unroll
    for (int s = 0; s < 8; ++s)
        async4(ecol + (size_t)(1 + s) * BB * NN, &sem[0][s][0]);

    // B fragments: Bf[g][kh], element j = 0.25*exp(trans[(32kh+8q+j)][16g+nlo]).
    // A-layout: A[m=lane&15][k2=8*(lane>>4)+j]; all 16 A-rows replicated.
    // C/D: col=lane&15, all rows equal -> lane k selects group k>>4 via cndmasks.
    half8_t Bf[4][2];
    #pragma unroll
    for (int g = 0; g < 4; ++g) {
        #pragma unroll
        for (int kh = 0; kh < 2; ++kh) {
            AFrag bf;
            #pragma unroll
            for (int jp = 0; jp < 4; ++jp) {
                const int krow = 32 * kh + 8 * q + 2 * jp;
                const float e0 = 0.25f * __expf(trans[(krow + 0) * NN + 16 * g + nlo]);
                const float e1 = 0.25f * __expf(trans[(krow + 1) * NN + 16 * g + nlo]);
                bf.u[jp] = __builtin_bit_cast(int, __builtin_amdgcn_cvt_pkrtz(e0, e1));
            }
            Bf[g][kh] = bf.h;
        }
    }

    // bpermute byte-addresses: A frag (kh, reg r) needs the f16 pair
    // (u_{32kh+8q+2r}, u_{...+2r+1}), held by (even) source lane 32kh+8q+2r.
    int addrs[8];
    #pragma unroll
    for (int kh = 0; kh < 2; ++kh)
        #pragma unroll
        for (int r = 0; r < 4; ++r)
            addrs[4 * kh + r] = 128 * kh + 32 * q + 8 * r;

    const f32x4 zero4 = {0.f, 0.f, 0.f, 0.f};

    // t = 0: u = exp(alpha0 - m0)
    const float alpha0 = ecol[0] + strans[k];
    const float m0 = bcast_lane(alpha0, 0);
    float u = __expf(alpha0 - m0);
    int e_sum = 0;

    // One exp-domain step.
    auto do_step = [&](float wloc) {
        // pack: even lane 2m forms (u_2m, u_2m+1); odd lanes' pkv never read
        // (bpermute sources are even lanes) — no cndmask needed.
        const float uo = __int_as_float(
            __builtin_amdgcn_mov_dpp(__float_as_int(u), 0xB1, 0xF, 0xF, true));
        const int pkv = __builtin_bit_cast(int, __builtin_amdgcn_cvt_pkrtz(u, uo));

        // gather A fragments (8 bpermutes, in-order LDS pipe)
        AFrag a0f, a1f;
        #pragma unroll
        for (int r = 0; r < 4; ++r) {
            a0f.u[r] = __builtin_amdgcn_ds_bpermute(addrs[r],     pkv);
            a1f.u[r] = __builtin_amdgcn_ds_bpermute(addrs[4 + r], pkv);
        }

        // y = u * 0.25E : 4 column groups; K-halves chained through C.
        const f32x4 accA0 = __builtin_amdgcn_mfma_f32_16x16x32_f16(a0f.h, Bf[0][0], zero4, 0, 0, 0);
        const f32x4 accA1 = __builtin_amdgcn_mfma_f32_16x16x32_f16(a0f.h, Bf[1][0], zero4, 0, 0, 0);
        const f32x4 accA2 = __builtin_amdgcn_mfma_f32_16x16x32_f16(a0f.h, Bf[2][0], zero4, 0, 0, 0);
        const f32x4 accA3 = __builtin_amdgcn_mfma_f32_16x16x32_f16(a0f.h, Bf[3][0], zero4, 0, 0, 0);
        const f32x4 acc0 = __builtin_amdgcn_mfma_f32_16x16x32_f16(a1f.h, Bf[0][1], accA0, 0, 0, 0);
        const f32x4 acc1 = __builtin_amdgcn_mfma_f32_16x16x32_f16(a1f.h, Bf[1][1], accA1, 0, 0, 0);
        const f32x4 acc2 = __builtin_amdgcn_mfma_f32_16x16x32_f16(a1f.h, Bf[2][1], accA2, 0, 0, 0);
        const f32x4 acc3 = __builtin_amdgcn_mfma_f32_16x16x32_f16(a1f.h, Bf[3][1], accA3, 0, 0, 0);

        // lane k takes column-group g = k>>4 (all D rows identical): 3 cndmasks
        const float sLo  = bit4 ? acc1[0] : acc0[0];
        const float sHi  = bit4 ? acc3[0] : acc2[0];
        const float yown = bit5 ? sHi : sLo;

        // e from lane0's PRE-w value (+4 guard) — readfirstlane/SALU path
        // overlaps the v_mul below.
        const int e = (int)((__builtin_amdgcn_readfirstlane(__float_as_uint(yown)) >> 23) & 0xff) - 127 + 4;
        const float y = yown * wloc;
        u = ldexpf(y, -e);
        e_sum += e + 2;   // +2 restores the 0.25=2^-2 folded into B (exact)
    };

    int t = 1;
    int half = 0;
    // Invariant at block top: rows t..t+7 are in sem[half][0..7] — their DMAs
    // were issued >= 1 block (~8 steps) ago, so the vmcnt wait is free.
    for (; t + 8 <= len; t += 8) {
        // (1) read this block's rows into registers (off the u-chain)
        float v0 = sem[half][0][k], v1 = sem[half][1][k];
        float v2 = sem[half][2][k], v3 = sem[half][3][k];
        float v4 = sem[half][4][k], v5 = sem[half][5][k];
        float v6 = sem[half][6][k], v7 = sem[half][7][k];

        // (2) issue next block's DMAs into the other half (clamped at TT-1;
        //     overshoot rows are never consumed)
        #pragma unroll
        for (int s = 0; s < 8; ++s) {
            const int tf = (t + 8 + s < TT) ? (t + 8 + s) : (TT - 1);
            async4(ecol + (size_t)tf * BB * NN, &sem[half ^ 1][s][0]);
        }

        // (3) exps off the u-chain, then 8 MFMA steps
        const float w0 = __expf(v0), w1 = __expf(v1), w2 = __expf(v2), w3 = __expf(v3);
        const float w4 = __expf(v4), w5 = __expf(v5), w6 = __expf(v6), w7 = __expf(v7);
        do_step(w0); do_step(w1); do_step(w2); do_step(w3);
        do_step(w4); do_step(w5); do_step(w6); do_step(w7);

        half ^= 1;
    }

    // Remainder (< 8 steps): rows t..len-1 are already in sem[half][...].
    for (int s = 0; t < len; ++t, ++s)
        do_step(__expf(sem[half][s][k]));

    // logZ_b = S + logsumexp_k(log(u_k) + etrans[k]),  S = m0 + ln2*e_sum
    const float la = __logf(u) + etrans[k];   // u==0 -> -inf -> exp -> 0: fine
    const float m2 = wave_max(la);
    const float sm = wave_sum(__expf(la - m2));
    const float logZ_b = m0 + LN2F * (float)e_sum + m2 + __logf(sm);

    // ---- fused gold score for batch b: lane k covers t = 64*i + k ----
    int tvals[TT / 64];
    #pragma unroll
    for (int i = 0; i < TT / 64; ++i)
        tvals[i] = target[(size_t)(64 * i + k) * BB + b];

    float g = 0.f;
    int prev_last = 0;
    #pragma unroll
    for (int i = 0; i < TT / 64; ++i) {
        const int tt = 64 * i + k;
        const int tgt = tvals[i];
        int tprev = __shfl_up(tvals[i], 1, 64);
        if (k == 0) tprev = prev_last;                       // carry across i
        prev_last = __builtin_amdgcn_readlane(tvals[i], 63);
        if (tt < len) {
            float v = emit[((size_t)tt * BB + b) * NN + tgt];
            v += (tt == 0) ? strans[tgt] : trans[tprev * NN + tgt];
            if (tt == len - 1) v += etrans[tgt];
            g += v;
        }
    }
    g = wave_sum(g);

    if (k == 0) atomicAdd(out, logZ_b - g);
}

extern "C" void kernel_launch(void* const* d_in, const int* in_sizes, int n_in,
                              void* d_out, int out_size, void* d_ws, size_t ws_size,
                              hipStream_t stream) {
    const float* emit   = (const float*)d_in[0];
    const float* trans  = (const float*)d_in[1];
    const float* strans = (const float*)d_in[2];
    const float* etrans = (const float*)d_in[3];
    const int*   target = (const int*)d_in[4];
    const void*  mask   = d_in[5];
    float* out = (float*)d_out;

    hipLaunchKernelGGL(zero_kernel, dim3(1), dim3(64), 0, stream, out);
    hipLaunchKernelGGL(crf_fwd_kernel, dim3(BB), dim3(64), 0, stream,
                       emit, trans, strans, etrans, target, mask, out);
}